// Round 1
// baseline (1273.337 us; speedup 1.0000x reference)
//
#include <hip/hip_runtime.h>
#include <math.h>

// PQLayer forward, MI355X.
//   x:     (B, 512) fp32      d_in[0]
//   C:     (64, 256, 8) fp32  d_in[1]
//   out0:  x_hat (B, 512) fp32            = C[m, k*, :]
//   out1:  codes (B, 64, 256) fp32        = one_hot(k*)
// Forward value of stop_gradient(hard - soft) + soft == hard (to <=1 ulp),
// so we compute only the argmax; no softmax needed.
//
// Layout: one wave per (m, chunk-of-64-b). lane = b within chunk, so the
// 256-way argmax is purely in-lane (no cross-lane reduce). C[m,k,:] loads are
// wave-uniform -> scalar s_load pipe; x is 8 VGPRs/lane held across the k-loop.
// codes rows are written 1 KB coalesced per wave store (readlane broadcast).

#define B_SZ   16384
#define FEAT   512
#define M_SZ   64
#define K_SZ   256
#define D_SZ   8

__global__ __launch_bounds__(256) void pq_fwd(
    const float* __restrict__ x,
    const float* __restrict__ C,
    float* __restrict__ xhat,
    float* __restrict__ codes)
{
    // Match numpy einsum's SSE float32 sum-of-products rounding exactly:
    // products rounded separately, pairwise tree sum, NO fma contraction.
#pragma clang fp contract(off)

    const int tid   = blockIdx.x * blockDim.x + threadIdx.x;
    const int wave  = tid >> 6;            // 0 .. 16383
    const int lane  = threadIdx.x & 63;
    const int m     = wave & (M_SZ - 1);   // sub-space
    const int chunk = wave >> 6;           // 0 .. 255
    const int b0    = chunk << 6;
    const int b     = b0 | lane;           // this lane's batch row

    // x[b, m*8 .. m*8+7] -> registers (strided 2 KB between lanes; 32 MB total)
    const float* xp = x + (size_t)b * FEAT + m * D_SZ;
    const float4 xa = *(const float4*)(xp);
    const float4 xb = *(const float4*)(xp + 4);

    const float* __restrict__ Cm = C + (size_t)m * (K_SZ * D_SZ);

    float best  = -INFINITY;
    int   bestk = 0;

#pragma unroll 4
    for (int k = 0; k < K_SZ; ++k) {
        const float* cr = Cm + k * D_SZ;   // wave-uniform -> s_load
        // s_i = round(x_i * c_i)  (separate roundings, no FMA)
        float s0 = xa.x * cr[0];
        float s1 = xa.y * cr[1];
        float s2 = xa.z * cr[2];
        float s3 = xa.w * cr[3];
        float s4 = xb.x * cr[4];
        float s5 = xb.y * cr[5];
        float s6 = xb.z * cr[6];
        float s7 = xb.w * cr[7];
        // numpy SSE tree: t_i = s_i + s_{i+4}; dot = (t0+t1)+(t2+t3)
        float t0 = s0 + s4;
        float t1 = s1 + s5;
        float t2 = s2 + s6;
        float t3 = s3 + s7;
        float dot = (t0 + t1) + (t2 + t3);
        // strict > keeps the first (lowest k) max -> matches np.argmax
        if (dot > best) { best = dot; bestk = k; }
    }

    // ---- x_hat[b, m*8 .. m*8+7] = C[m, bestk, :]  (divergent gather, L2-hot) ----
    {
        const float* cw = Cm + bestk * D_SZ;
        const float4 h0 = *(const float4*)(cw);
        const float4 h1 = *(const float4*)(cw + 4);
        float* xh = xhat + (size_t)b * FEAT + m * D_SZ;
        *(float4*)(xh)     = h0;
        *(float4*)(xh + 4) = h1;
    }

    // ---- codes: one-hot rows, 1 KB coalesced per wave store ----
    // Row for pair (b0+j, m): all 64 lanes cooperate; lane holds k = 4*lane..4*lane+3.
    const int lane4 = lane << 2;
    float* const codes_base = codes + ((size_t)b0 * M_SZ + m) * K_SZ + lane4;
    for (int j = 0; j < 64; ++j) {
        const int kj = __builtin_amdgcn_readlane(bestk, j);  // broadcast pair j's argmax
        float4 v;
        v.x = (kj == lane4 + 0) ? 1.0f : 0.0f;
        v.y = (kj == lane4 + 1) ? 1.0f : 0.0f;
        v.z = (kj == lane4 + 2) ? 1.0f : 0.0f;
        v.w = (kj == lane4 + 3) ? 1.0f : 0.0f;
        *(float4*)(codes_base + (size_t)j * (M_SZ * K_SZ)) = v;
    }
}

extern "C" void kernel_launch(void* const* d_in, const int* in_sizes, int n_in,
                              void* d_out, int out_size, void* d_ws, size_t ws_size,
                              hipStream_t stream)
{
    const float* x = (const float*)d_in[0];
    const float* C = (const float*)d_in[1];
    float* xhat  = (float*)d_out;                              // (B, 512)
    float* codes = (float*)d_out + (size_t)B_SZ * FEAT;        // (B, 64, 256)

    // 16384 waves = M(64) * B/64(256); 4 waves/block -> 4096 blocks of 256.
    const dim3 grid(4096), block(256);
    hipLaunchKernelGGL(pq_fwd, grid, block, 0, stream, x, C, xhat, codes);
}

// Round 2
// 1212.278 us; speedup vs baseline: 1.0504x; 1.0504x over previous
//
#include <hip/hip_runtime.h>
#include <math.h>

// PQLayer forward, MI355X — two-kernel split.
//   x:     (B, 512) fp32      d_in[0]
//   C:     (64, 256, 8) fp32  d_in[1]
//   out0:  x_hat (B, 512) fp32     = C[m, k*, :]
//   out1:  codes (B, 64, 256) fp32 = one_hot(k*)    [1.07 GB -> dominates]
//
// stop_gradient(hard - soft) + soft == hard in fp32 forward (<=1 ulp), so only
// the argmax matters. Kernel 1 computes bestk(b,m) -> 1 MB u8 in d_ws
// (C staged in LDS, np-exact product/sum tree, contract off). Kernel 2 is a
// pure streaming writer: wave = b writes codes[b,:,:] as one LINEAR 64 KB run
// (R0's 64KB-strided scatter ran at 0.9 TB/s; linear streams hit ~6.3 TB/s).

#define B_SZ   16384
#define FEAT   512
#define M_SZ   64
#define K_SZ   256
#define D_SZ   8

// ---------------- Kernel 1: argmax only ----------------
// grid: 64 m * 64 chunks = 4096 blocks of 256 threads; thread = one b.
__global__ __launch_bounds__(256) void pq_argmax(
    const float* __restrict__ x,
    const float* __restrict__ C,
    unsigned char* __restrict__ bestk8)
{
#pragma clang fp contract(off)   // np einsum: separate product roundings, no FMA

    const int m     = blockIdx.x & (M_SZ - 1);
    const int chunk = blockIdx.x >> 6;
    const int t     = threadIdx.x;
    const int b     = (chunk << 8) | t;

    // Stage C[m] (8 KB) in LDS; k-loop reads are wave-uniform -> LDS broadcast.
    __shared__ float lC[K_SZ * D_SZ];
    {
        const float4* src = (const float4*)(C + (size_t)m * (K_SZ * D_SZ));
        float4* dst = (float4*)lC;
        dst[t]       = src[t];
        dst[t + 256] = src[t + 256];
    }
    __syncthreads();

    const float* xp = x + (size_t)b * FEAT + m * D_SZ;
    const float4 xa = *(const float4*)(xp);
    const float4 xb = *(const float4*)(xp + 4);

    float best  = -INFINITY;
    int   bestk = 0;

#pragma unroll 4
    for (int k = 0; k < K_SZ; ++k) {
        const float* cr = lC + k * D_SZ;
        float s0 = xa.x * cr[0];
        float s1 = xa.y * cr[1];
        float s2 = xa.z * cr[2];
        float s3 = xa.w * cr[3];
        float s4 = xb.x * cr[4];
        float s5 = xb.y * cr[5];
        float s6 = xb.z * cr[6];
        float s7 = xb.w * cr[7];
        float t0 = s0 + s4;              // np SSE pairwise tree
        float t1 = s1 + s5;
        float t2 = s2 + s6;
        float t3 = s3 + s7;
        float dot = (t0 + t1) + (t2 + t3);
        if (dot > best) { best = dot; bestk = k; }   // strict >: first max, like np.argmax
    }

    bestk8[(size_t)b * M_SZ + m] = (unsigned char)bestk;  // 1 MB total, via L2
}

// ---------------- Kernel 2: streaming writer ----------------
// wave = b. lane l: m = l for xhat; codes written m-major -> linear 64 KB/wave.
__global__ __launch_bounds__(256) void pq_write(
    const float* __restrict__ C,
    const unsigned char* __restrict__ bestk8,
    float* __restrict__ xhat,
    float* __restrict__ codes)
{
    const int tid  = blockIdx.x * blockDim.x + threadIdx.x;
    const int b    = tid >> 6;
    const int lane = threadIdx.x & 63;

    // lane l holds bestk(b, m=l); 64 B coalesced load per wave
    const int kb = (int)bestk8[(size_t)b * M_SZ + lane];

    // ---- xhat[b, l*8 .. l*8+7] = C[l, kb, :] (gather from L1/L2-hot C) ----
    {
        const float* cw = C + ((size_t)lane * K_SZ + kb) * D_SZ;
        const float4 h0 = *(const float4*)(cw);
        const float4 h1 = *(const float4*)(cw + 4);
        float* xh = xhat + (size_t)b * FEAT + lane * D_SZ;
        *(float4*)(xh)     = h0;
        *(float4*)(xh + 4) = h1;
    }

    // ---- codes[b, m, :]: 64 consecutive 1 KB wave-stores = linear 64 KB ----
    const int lane4 = lane << 2;
    float* const base = codes + (size_t)b * (M_SZ * K_SZ) + lane4;
#pragma unroll 8
    for (int m = 0; m < M_SZ; ++m) {
        const int kj = __builtin_amdgcn_readlane(kb, m);
        float4 v;
        v.x = (kj == lane4 + 0) ? 1.0f : 0.0f;
        v.y = (kj == lane4 + 1) ? 1.0f : 0.0f;
        v.z = (kj == lane4 + 2) ? 1.0f : 0.0f;
        v.w = (kj == lane4 + 3) ? 1.0f : 0.0f;
        *(float4*)(base + (size_t)m * K_SZ) = v;
    }
}

extern "C" void kernel_launch(void* const* d_in, const int* in_sizes, int n_in,
                              void* d_out, int out_size, void* d_ws, size_t ws_size,
                              hipStream_t stream)
{
    const float* x = (const float*)d_in[0];
    const float* C = (const float*)d_in[1];
    float* xhat  = (float*)d_out;                           // (B, 512)
    float* codes = (float*)d_out + (size_t)B_SZ * FEAT;     // (B, 64, 256)
    unsigned char* bestk8 = (unsigned char*)d_ws;           // (B, 64) u8 = 1 MB

    hipLaunchKernelGGL(pq_argmax, dim3(4096), dim3(256), 0, stream, x, C, bestk8);
    hipLaunchKernelGGL(pq_write,  dim3(4096), dim3(256), 0, stream, C, bestk8, xhat, codes);
}